// Round 11
// baseline (935.438 us; speedup 1.0000x reference)
//
#include <hip/hip_runtime.h>
#include <cstdint>

#define KNN 20
#define BV 8
#define NV 1024

// ---- DPP wave64 reduce helpers (rocPRIM pattern): result broadcast via readlane 63.
template <int CTRL>
__device__ __forceinline__ unsigned dppmax(unsigned x) {
    unsigned m = (unsigned)__builtin_amdgcn_update_dpp((int)x, (int)x, CTRL, 0xf, 0xf, false);
    return (x > m) ? x : m;
}
template <int CTRL>
__device__ __forceinline__ unsigned dppmin(unsigned x) {
    unsigned m = (unsigned)__builtin_amdgcn_update_dpp((int)x, (int)x, CTRL, 0xf, 0xf, false);
    return (x < m) ? x : m;
}
__device__ __forceinline__ unsigned wave_max_u32(unsigned x) {
    x = dppmax<0xB1>(x); x = dppmax<0x4E>(x); x = dppmax<0x141>(x);
    x = dppmax<0x140>(x); x = dppmax<0x142>(x); x = dppmax<0x143>(x);
    return (unsigned)__builtin_amdgcn_readlane((int)x, 63);
}
__device__ __forceinline__ unsigned wave_min_u32(unsigned x) {
    x = dppmin<0xB1>(x); x = dppmin<0x4E>(x); x = dppmin<0x141>(x);
    x = dppmin<0x140>(x); x = dppmin<0x142>(x); x = dppmin<0x143>(x);
    return (unsigned)__builtin_amdgcn_readlane((int)x, 63);
}

// ---------- transpose x [B,N,3] -> hx [B,3,N]
__global__ __launch_bounds__(256) void k_transpose(const float* __restrict__ x, float* __restrict__ hx) {
    int id = blockIdx.x * 256 + threadIdx.x;
    if (id >= BV * 3 * NV) return;
    int n = id % NV;
    int c = (id / NV) % 3;
    int b = id / (3 * NV);
    hx[id] = x[(b * NV + n) * 3 + c];
}

// ---------- xx[b][n] = sum_c h[b][c][n]^2
__global__ __launch_bounds__(256) void k_xx(const float* __restrict__ h, float* __restrict__ xx,
                                            int C, int bstride) {
    int id = blockIdx.x * 256 + threadIdx.x;
    int n = id % NV, b = id / NV;
    if (b >= BV) return;
    const float* hp = h + (size_t)b * bstride + n;
    float s = 0.f;
    for (int c = 0; c < C; ++c) { float v = hp[(size_t)c * NV]; s += v * v; }
    xx[b * NV + n] = s;
}

// ---------- FUSED kNN over a j-QUARTER (256 cols): per row, sorted top-20 of the quarter.
// 1D grid 1024 blocks: b = bx&7 (XCD-local batch), quarter = (bx>>3)&3, tile = bx>>5.
// block 512 = 8 waves; wave w owns rows i0+4w..+3; lane owns 4 contiguous j's (conflict-free b128).
// 4 blocks/CU, 8 waves/SIMD.
__global__ __launch_bounds__(512, 8) void k_knn(const float* __restrict__ h, const float* __restrict__ xx,
                                                int C, int bstride,
                                                unsigned* __restrict__ sval, int* __restrict__ sidx) {
    __shared__ float Bs[8][256];
    __shared__ float As[8][32];
    const int bx = blockIdx.x;
    const int tile = bx >> 5, panel = bx & 31;
    const int b = panel & 7, quarter = panel >> 3;
    const int i0 = tile * 32, jbase = quarter * 256;
    const int t = threadIdx.x, lane = t & 63, w = t >> 6;
    const int irow = i0 + w * 4;
    float acc[4][4] = {};
    const float* hb = h + (size_t)b * bstride;

    for (int c0 = 0; c0 < C; c0 += 8) {
        __syncthreads();
        {   // Bs[8][256] = 512 float4, one per thread; wave w loads channel row c0+w (coalesced 1KB)
            int cc = t >> 6, g = t & 63;
            float4 v = make_float4(0.f, 0.f, 0.f, 0.f);
            if (c0 + cc < C) v = *(const float4*)&hb[(size_t)(c0 + cc) * NV + jbase + g * 4];
            *(float4*)&Bs[cc][g * 4] = v;
        }
        if (t < 64) {   // As[8][32]: A-side rows i0..i0+31
#pragma unroll
            for (int r = 0; r < 4; ++r) {
                int e = r * 64 + t;
                int cc = e >> 5, ii = e & 31;
                As[cc][ii] = (c0 + cc < C) ? hb[(size_t)(c0 + cc) * NV + i0 + ii] : 0.f;
            }
        }
        __syncthreads();
#pragma unroll
        for (int c = 0; c < 8; ++c) {
            float4 arv = *(const float4*)&As[c][w * 4];    // wave-uniform broadcast
            float ar[4] = {arv.x, arv.y, arv.z, arv.w};
            float4 bv = *(const float4*)&Bs[c][lane * 4];  // 16B/lane stride-1: conflict-free
            float br[4] = {bv.x, bv.y, bv.z, bv.w};
#pragma unroll
            for (int a = 0; a < 4; ++a)
#pragma unroll
                for (int q = 0; q < 4; ++q) acc[a][q] += ar[a] * br[q];
        }
    }

    // neg sqdist = 2*dot - xx_i - xx_j
    const float* xb = xx + b * NV;
    float4 xv = *(const float4*)&xb[jbase + lane * 4];
    float xxj[4] = {xv.x, xv.y, xv.z, xv.w};
#pragma unroll
    for (int a = 0; a < 4; ++a) {
        float xi = xb[irow + a];
#pragma unroll
        for (int q = 0; q < 4; ++q) acc[a][q] = 2.f * acc[a][q] - xi - xxj[q];
    }

    // ---- wave-parallel top-20 of this quarter, 4 rows interleaved, all-VALU
#pragma unroll 1
    for (int s = 0; s < KNN; ++s) {
#pragma unroll
        for (int a = 0; a < 4; ++a) {
            // local argmax over 4 regs: tree, leftmost-max => lowest q on tie
            bool g0 = acc[a][1] > acc[a][0];
            float v0 = g0 ? acc[a][1] : acc[a][0]; int q0 = g0 ? 1 : 0;
            bool g1 = acc[a][3] > acc[a][2];
            float v1 = g1 ? acc[a][3] : acc[a][2]; int q1 = g1 ? 3 : 2;
            bool gf = v1 > v0;
            float bv = gf ? v1 : v0;
            int bq = gf ? q1 : q0;

            unsigned u = __float_as_uint(bv);
            unsigned su = ((int)u < 0) ? ~u : (u | 0x80000000u);   // sortable uint
            int myj = jbase + (lane << 2) + bq;                     // global j (unique per lane)
            unsigned gmax = wave_max_u32(su);
            unsigned cand = (su == gmax) ? (unsigned)myj : 0xFFFFFFFFu;
            int j = (int)wave_min_u32(cand);
            if (lane == 0) {
                size_t o = ((size_t)(b * NV + irow + a) * 4 + quarter) * KNN + s;
                sval[o] = gmax;
                sidx[o] = j;
            }
            int wq = (myj == j) ? bq : 9;   // winner lane poisons its slot
#pragma unroll
            for (int q = 0; q < 4; ++q)
                if (wq == q) acc[a][q] = -3.4e38f;
        }
    }
}

// ---------- merge four sorted per-quarter top-20 lists -> global top-20 (exact ties)
__global__ __launch_bounds__(256) void k_merge(const unsigned* __restrict__ sval,
                                               const int* __restrict__ sidx,
                                               int* __restrict__ idx) {
    int row = blockIdx.x * 256 + threadIdx.x;
    if (row >= BV * NV) return;
    const unsigned* v = sval + (size_t)row * 4 * KNN;
    const int* ii = sidx + (size_t)row * 4 * KNN;
    int pos[4] = {0, 0, 0, 0};
    unsigned hv[4]; int hj[4];
#pragma unroll
    for (int l = 0; l < 4; ++l) { hv[l] = v[l * KNN]; hj[l] = ii[l * KNN]; }
    int* op = idx + (size_t)row * KNN;
#pragma unroll 1
    for (int s = 0; s < KNN; ++s) {
        bool b01 = (hv[1] > hv[0]) || (hv[1] == hv[0] && hj[1] < hj[0]);
        unsigned v01 = b01 ? hv[1] : hv[0]; int j01 = b01 ? hj[1] : hj[0]; int l01 = b01 ? 1 : 0;
        bool b23 = (hv[3] > hv[2]) || (hv[3] == hv[2] && hj[3] < hj[2]);
        unsigned v23 = b23 ? hv[3] : hv[2]; int j23 = b23 ? hj[3] : hj[2]; int l23 = b23 ? 3 : 2;
        bool bf = (v23 > v01) || (v23 == v01 && j23 < j01);
        int win = bf ? l23 : l01;
        op[s] = bf ? j23 : j01;
#pragma unroll
        for (int l = 0; l < 4; ++l) {
            if (win == l) {
                int np = pos[l] + 1; pos[l] = np;
                bool ok = np < KNN;
                hv[l] = ok ? v[l * KNN + np] : 0u;            // sentinel: smaller than any real
                hj[l] = ok ? ii[l * KNN + np] : 0x7FFFFFFF;
            }
        }
    }
}

// ---------- pack A = [ Wl ; Wr - Wl ]  (2O x C)
__global__ __launch_bounds__(256) void k_pack(const float* __restrict__ W, float* __restrict__ wb,
                                              int C, int O) {
    int id = blockIdx.x * 256 + threadIdx.x;
    if (id >= 2 * O * C) return;
    int c = id % C, o = (id / C) % O, half = id / (C * O);
    float wl = W[(size_t)o * 2 * C + c];
    wb[id] = half ? (W[(size_t)o * 2 * C + C + c] - wl) : wl;
}

// ---------- out[b][o][n] = sum_c A[o][c] * h[b][c][n]   (64x128 tile, 4x8 micro)
// grid (8 b, 8 ntile, 2O/64): b fastest -> XCD-local batch panels.
__global__ __launch_bounds__(256) void k_gemm(const float* __restrict__ A, int astride,
                                              const float* __restrict__ h, int bstride, int C,
                                              float* __restrict__ out, int O) {
    __shared__ float Ws[8][64], Hs[8][128];
    const int b = blockIdx.x, n0 = blockIdx.y * 128, o0 = blockIdx.z * 64;
    const int t = threadIdx.x, tx = t & 15, ty = t >> 4;
    float acc[4][8] = {};
    const float* hb = h + (size_t)b * bstride;
    for (int c0 = 0; c0 < C; c0 += 8) {
#pragma unroll
        for (int q = 0; q < 2; ++q) {
            int e = t + q * 256;
            int oo = e >> 3, cc = e & 7;
            Ws[cc][oo] = ((c0 + cc) < C) ? A[(size_t)(o0 + oo) * astride + c0 + cc] : 0.f;
        }
        {
            int cc = t >> 5, nn4 = t & 31;
            float4 v = make_float4(0.f, 0.f, 0.f, 0.f);
            if (c0 + cc < C) v = *(const float4*)&hb[(size_t)(c0 + cc) * NV + n0 + nn4 * 4];
            *(float4*)&Hs[cc][nn4 * 4] = v;
        }
        __syncthreads();
#pragma unroll
        for (int c = 0; c < 8; ++c) {
            float4 wv = *(const float4*)&Ws[c][ty * 4];
            float ar[4] = {wv.x, wv.y, wv.z, wv.w};
            float br[8];
            float4 h0 = *(const float4*)&Hs[c][tx * 4];
            float4 h1 = *(const float4*)&Hs[c][64 + tx * 4];
            br[0] = h0.x; br[1] = h0.y; br[2] = h0.z; br[3] = h0.w;
            br[4] = h1.x; br[5] = h1.y; br[6] = h1.z; br[7] = h1.w;
#pragma unroll
            for (int a = 0; a < 4; ++a)
#pragma unroll
                for (int q = 0; q < 8; ++q) acc[a][q] += ar[a] * br[q];
        }
        __syncthreads();
    }
#pragma unroll
    for (int a = 0; a < 4; ++a) {
        int o = o0 + ty * 4 + a;
        float* outp = out + ((size_t)b * O + o) * NV + n0;
        float4 s0 = make_float4(acc[a][0], acc[a][1], acc[a][2], acc[a][3]);
        float4 s1 = make_float4(acc[a][4], acc[a][5], acc[a][6], acc[a][7]);
        *(float4*)&outp[tx * 4] = s0;
        *(float4*)&outp[64 + tx * 4] = s1;
    }
}

// ---------- h_out[b][o][n] = mean_k lrelu( a*(p[b][o][idx[n][k]] + d[b][o][n]) + c0 )
// grid (8 b, 4 ntile, O/4): thread handles 4 o's for one n -> idx loaded once.
__global__ __launch_bounds__(256) void k_edge(const float* __restrict__ pd,
                                              const int* __restrict__ idx,
                                              const float* __restrict__ ga, const float* __restrict__ be,
                                              const float* __restrict__ mu, const float* __restrict__ va,
                                              float* __restrict__ out, int out_bstride, int O) {
    const int b = blockIdx.x;
    const int n = blockIdx.y * 256 + threadIdx.x;
    const int o0 = blockIdx.z * 4;
    const int* ip = idx + ((size_t)b * NV + n) * KNN;
    int jj[KNN];
#pragma unroll
    for (int k = 0; k < KNN; ++k) jj[k] = ip[k];
#pragma unroll
    for (int a = 0; a < 4; ++a) {
        const int o = o0 + a;
        const float al = ga[o] / sqrtf(va[o] + 1e-5f);
        const float c0 = be[o] - mu[o] * al;
        const float* pb = pd + ((size_t)b * 2 * O + o) * NV;
        const float dv  = pd[((size_t)b * 2 * O + O + o) * NV + n];
        float s = 0.f;
#pragma unroll
        for (int k = 0; k < KNN; ++k) {
            float y = fmaf(al, pb[jj[k]] + dv, c0);
            s += (y > 0.f) ? y : 0.2f * y;
        }
        out[(size_t)b * out_bstride + (size_t)o * NV + n] = s * (1.f / KNN);
    }
}

// ---------- pooled[b][o] = mean_n hf[b][o][n]
__global__ __launch_bounds__(256) void k_pool(const float* __restrict__ hf, float* __restrict__ pooled) {
    const int o = blockIdx.x, b = blockIdx.y;
    const float* hp = hf + ((size_t)b * 512 + o) * NV;
    float s = 0.f;
    for (int i = threadIdx.x; i < NV; i += 256) s += hp[i];
#pragma unroll
    for (int off = 32; off > 0; off >>= 1) s += __shfl_down(s, off, 64);
    __shared__ float red[4];
    if ((threadIdx.x & 63) == 0) red[threadIdx.x >> 6] = s;
    __syncthreads();
    if (threadIdx.x == 0)
        pooled[(size_t)b * 512 + o] = (red[0] + red[1] + red[2] + red[3]) * (1.f / NV);
}

// ---------- out[b][j] = sum_o pooled[b][o] * We[j][o]
__global__ __launch_bounds__(256) void k_final(const float* __restrict__ pooled, const float* __restrict__ We,
                                               float* __restrict__ out) {
    const int j = threadIdx.x, b = blockIdx.x;
    __shared__ float ps[512];
    for (int o = threadIdx.x; o < 512; o += 256) ps[o] = pooled[b * 512 + o];
    __syncthreads();
    float s = 0.f;
    for (int o = 0; o < 512; ++o) s += ps[o] * We[(size_t)j * 512 + o];
    out[b * 256 + j] = s;
}

extern "C" void kernel_launch(void* const* d_in, const int* in_sizes, int n_in,
                              void* d_out, int out_size, void* d_ws, size_t ws_size,
                              hipStream_t stream) {
    const float* x  = (const float*)d_in[0];
    const float* W0 = (const float*)d_in[1];
    const float* g0 = (const float*)d_in[2];
    const float* b0 = (const float*)d_in[3];
    const float* m0 = (const float*)d_in[4];
    const float* v0 = (const float*)d_in[5];
    const float* W1 = (const float*)d_in[6];
    const float* g1 = (const float*)d_in[7];
    const float* b1 = (const float*)d_in[8];
    const float* m1 = (const float*)d_in[9];
    const float* v1 = (const float*)d_in[10];
    const float* W2 = (const float*)d_in[11];
    const float* g2 = (const float*)d_in[12];
    const float* b2 = (const float*)d_in[13];
    const float* m2 = (const float*)d_in[14];
    const float* v2 = (const float*)d_in[15];
    const float* Wf = (const float*)d_in[16];
    const float* gf = (const float*)d_in[17];
    const float* bf = (const float*)d_in[18];
    const float* mf = (const float*)d_in[19];
    const float* vf = (const float*)d_in[20];
    const float* We = (const float*)d_in[21];

    float* ws = (float*)d_ws;
    float* hx     = ws;                          // 24576
    float* cat    = hx + 24576;                  // 3670016
    float* xx     = cat + 3670016;               // 8192
    int*   idx    = (int*)(xx + 8192);           // 163840 ints
    float* pd     = (float*)(idx + 163840);      // 8388608 (2O max = 1024)
    float* wb     = pd + 8388608;                // 458752
    float* hf     = wb + 458752;                 // 4194304
    float* pooled = hf + 4194304;                // 4096
    unsigned* sval = (unsigned*)(pooled + 4096); // 8192*4*20 = 655360
    int*      sidx = (int*)(sval + 655360);      // 655360

    k_transpose<<<96, 256, 0, stream>>>(x, hx);

    auto run_layer = [&](const float* h, int C, int bstride, const float* W,
                         const float* g, const float* be, const float* m, const float* v,
                         int O, float* outp, int obstride) {
        k_xx<<<32, 256, 0, stream>>>(h, xx, C, bstride);
        k_knn<<<1024, 512, 0, stream>>>(h, xx, C, bstride, sval, sidx);
        k_merge<<<32, 256, 0, stream>>>(sval, sidx, idx);
        int pn = 2 * O * C;
        k_pack<<<(pn + 255) / 256, 256, 0, stream>>>(W, wb, C, O);
        k_gemm<<<dim3(8, 8, 2 * O / 64), 256, 0, stream>>>(wb, C, h, bstride, C, pd, 2 * O);
        k_edge<<<dim3(8, 4, O / 4), 256, 0, stream>>>(pd, idx, g, be, m, v, outp, obstride, O);
    };

    run_layer(hx, 3, 3 * NV, W0, g0, b0, m0, v0, 64, cat, 448 * NV);
    run_layer(cat, 64, 448 * NV, W1, g1, b1, m1, v1, 128, cat + 64 * NV, 448 * NV);
    run_layer(cat + 64 * NV, 128, 448 * NV, W2, g2, b2, m2, v2, 256, cat + 192 * NV, 448 * NV);
    run_layer(cat, 448, 448 * NV, Wf, gf, bf, mf, vf, 512, hf, 512 * NV);

    k_pool<<<dim3(512, 8), 256, 0, stream>>>(hf, pooled);
    k_final<<<8, 256, 0, stream>>>(pooled, We, (float*)d_out);
}

// Round 12
// 878.693 us; speedup vs baseline: 1.0646x; 1.0646x over previous
//
#include <hip/hip_runtime.h>
#include <cstdint>

#define KNN 20
#define BV 8
#define NV 1024

// ---- DPP wave64 max-reduce (rocPRIM pattern): result broadcast via readlane 63.
template <int CTRL>
__device__ __forceinline__ unsigned dppmax(unsigned x) {
    unsigned m = (unsigned)__builtin_amdgcn_update_dpp((int)x, (int)x, CTRL, 0xf, 0xf, false);
    return (x > m) ? x : m;
}
__device__ __forceinline__ unsigned wave_max_u32(unsigned x) {
    x = dppmax<0xB1>(x); x = dppmax<0x4E>(x); x = dppmax<0x141>(x);
    x = dppmax<0x140>(x); x = dppmax<0x142>(x); x = dppmax<0x143>(x);
    return (unsigned)__builtin_amdgcn_readlane((int)x, 63);
}

// ---------- transpose x [B,N,3] -> hx [B,3,N]
__global__ __launch_bounds__(256) void k_transpose(const float* __restrict__ x, float* __restrict__ hx) {
    int id = blockIdx.x * 256 + threadIdx.x;
    if (id >= BV * 3 * NV) return;
    int n = id % NV;
    int c = (id / NV) % 3;
    int b = id / (3 * NV);
    hx[id] = x[(b * NV + n) * 3 + c];
}

// ---------- xx[b][n] = sum_c h[b][c][n]^2
__global__ __launch_bounds__(256) void k_xx(const float* __restrict__ h, float* __restrict__ xx,
                                            int C, int bstride) {
    int id = blockIdx.x * 256 + threadIdx.x;
    int n = id % NV, b = id / NV;
    if (b >= BV) return;
    const float* hp = h + (size_t)b * bstride + n;
    float s = 0.f;
    for (int c = 0; c < C; ++c) { float v = hp[(size_t)c * NV]; s += v * v; }
    xx[b * NV + n] = s;
}

// ---------- FUSED kNN over a j-QUARTER (256 cols): per row, sorted top-20 of the quarter.
// 1D grid 512 blocks: b = bx&7 (XCD-local), quarter = (bx>>3)&3, tile = bx>>5 (64 rows).
// block 512 = 8 waves; wave w owns rows i0+8w..+7 (acc[8][4]); lane owns 4 contiguous j's.
__global__ __launch_bounds__(512, 4) void k_knn(const float* __restrict__ h, const float* __restrict__ xx,
                                                int C, int bstride,
                                                unsigned* __restrict__ sval, int* __restrict__ sidx) {
    __shared__ float Bs[8][256];
    __shared__ float As[8][64];
    const int bx = blockIdx.x;
    const int tile = bx >> 5, panel = bx & 31;
    const int b = panel & 7, quarter = panel >> 3;
    const int i0 = tile * 64, jbase = quarter * 256;
    const int t = threadIdx.x, lane = t & 63, w = t >> 6;
    const int irow = i0 + w * 8;
    float acc[8][4] = {};
    const float* hb = h + (size_t)b * bstride;

    for (int c0 = 0; c0 < C; c0 += 8) {
        __syncthreads();
        {   // Bs[8][256]: 512 float4, one per thread (coalesced 1KB per wave-row)
            int cc = t >> 6, g = t & 63;
            float4 v = make_float4(0.f, 0.f, 0.f, 0.f);
            if (c0 + cc < C) v = *(const float4*)&hb[(size_t)(c0 + cc) * NV + jbase + g * 4];
            *(float4*)&Bs[cc][g * 4] = v;
        }
        if (t < 128) {   // As[8][64]: A-side rows i0..i0+63, 128 float4
            int cc = t >> 4, ii = (t & 15) * 4;
            float4 v = make_float4(0.f, 0.f, 0.f, 0.f);
            if (c0 + cc < C) v = *(const float4*)&hb[(size_t)(c0 + cc) * NV + i0 + ii];
            *(float4*)&As[cc][ii] = v;
        }
        __syncthreads();
#pragma unroll
        for (int c = 0; c < 8; ++c) {
            float4 a0 = *(const float4*)&As[c][w * 8];       // wave-uniform broadcast
            float4 a1 = *(const float4*)&As[c][w * 8 + 4];
            float ar[8] = {a0.x, a0.y, a0.z, a0.w, a1.x, a1.y, a1.z, a1.w};
            float4 bv = *(const float4*)&Bs[c][lane * 4];    // 16B/lane stride-1: conflict-free
            float br[4] = {bv.x, bv.y, bv.z, bv.w};
#pragma unroll
            for (int a = 0; a < 8; ++a)
#pragma unroll
                for (int q = 0; q < 4; ++q) acc[a][q] += ar[a] * br[q];
        }
    }

    // neg sqdist = 2*dot - xx_i - xx_j
    const float* xb = xx + b * NV;
    float4 xv = *(const float4*)&xb[jbase + lane * 4];
    float xxj[4] = {xv.x, xv.y, xv.z, xv.w};
#pragma unroll
    for (int a = 0; a < 8; ++a) {
        float xi = xb[irow + a];
#pragma unroll
        for (int q = 0; q < 4; ++q) acc[a][q] = 2.f * acc[a][q] - xi - xxj[q];
    }

    // ---- wave-parallel top-20 of this quarter, 8 rows interleaved, all-VALU.
    // Index resolve: myj strictly increases with lane, so lowest set bit of the
    // ballot of value-matching lanes IS the lowest-index winner (exact ties).
#pragma unroll 1
    for (int s = 0; s < KNN; ++s) {
#pragma unroll
        for (int a = 0; a < 8; ++a) {
            // local argmax over 4 regs: tree, leftmost-max => lowest q on tie
            bool g0 = acc[a][1] > acc[a][0];
            float v0 = g0 ? acc[a][1] : acc[a][0]; int q0 = g0 ? 1 : 0;
            bool g1 = acc[a][3] > acc[a][2];
            float v1 = g1 ? acc[a][3] : acc[a][2]; int q1 = g1 ? 3 : 2;
            bool gf = v1 > v0;
            float bv = gf ? v1 : v0;
            int bq = gf ? q1 : q0;

            unsigned u = __float_as_uint(bv);
            unsigned su = ((int)u < 0) ? ~u : (u | 0x80000000u);   // sortable uint
            unsigned gmax = wave_max_u32(su);
            unsigned long long m = __ballot(su == gmax);
            int wl = (int)__ffsll(m) - 1;                           // lowest lane = lowest j
            int myj = jbase + (lane << 2) + bq;
            int j = __builtin_amdgcn_readlane(myj, wl);
            if (lane == 0) {
                size_t o = ((size_t)(b * NV + irow + a) * 4 + quarter) * KNN + s;
                sval[o] = gmax;
                sidx[o] = j;
            }
            int wq = (lane == wl) ? bq : 9;   // winner lane poisons its slot
#pragma unroll
            for (int q = 0; q < 4; ++q)
                if (wq == q) acc[a][q] = -3.4e38f;
        }
    }
}

// ---------- merge four sorted per-quarter top-20 lists -> global top-20 (exact ties)
__global__ __launch_bounds__(256) void k_merge(const unsigned* __restrict__ sval,
                                               const int* __restrict__ sidx,
                                               int* __restrict__ idx) {
    int row = blockIdx.x * 256 + threadIdx.x;
    if (row >= BV * NV) return;
    const unsigned* v = sval + (size_t)row * 4 * KNN;
    const int* ii = sidx + (size_t)row * 4 * KNN;
    int pos[4] = {0, 0, 0, 0};
    unsigned hv[4]; int hj[4];
#pragma unroll
    for (int l = 0; l < 4; ++l) { hv[l] = v[l * KNN]; hj[l] = ii[l * KNN]; }
    int* op = idx + (size_t)row * KNN;
#pragma unroll 1
    for (int s = 0; s < KNN; ++s) {
        bool b01 = (hv[1] > hv[0]) || (hv[1] == hv[0] && hj[1] < hj[0]);
        unsigned v01 = b01 ? hv[1] : hv[0]; int j01 = b01 ? hj[1] : hj[0]; int l01 = b01 ? 1 : 0;
        bool b23 = (hv[3] > hv[2]) || (hv[3] == hv[2] && hj[3] < hj[2]);
        unsigned v23 = b23 ? hv[3] : hv[2]; int j23 = b23 ? hj[3] : hj[2]; int l23 = b23 ? 3 : 2;
        bool bf = (v23 > v01) || (v23 == v01 && j23 < j01);
        int win = bf ? l23 : l01;
        op[s] = bf ? j23 : j01;
#pragma unroll
        for (int l = 0; l < 4; ++l) {
            if (win == l) {
                int np = pos[l] + 1; pos[l] = np;
                bool ok = np < KNN;
                hv[l] = ok ? v[l * KNN + np] : 0u;            // sentinel
                hj[l] = ok ? ii[l * KNN + np] : 0x7FFFFFFF;
            }
        }
    }
}

// ---------- pack A = [ Wl ; Wr - Wl ]  (2O x C)
__global__ __launch_bounds__(256) void k_pack(const float* __restrict__ W, float* __restrict__ wb,
                                              int C, int O) {
    int id = blockIdx.x * 256 + threadIdx.x;
    if (id >= 2 * O * C) return;
    int c = id % C, o = (id / C) % O, half = id / (C * O);
    float wl = W[(size_t)o * 2 * C + c];
    wb[id] = half ? (W[(size_t)o * 2 * C + C + c] - wl) : wl;
}

// ---------- out[b][o][n] = sum_c A[o][c] * h[b][c][n]   (64x128 tile, 4x8 micro)
__global__ __launch_bounds__(256) void k_gemm(const float* __restrict__ A, int astride,
                                              const float* __restrict__ h, int bstride, int C,
                                              float* __restrict__ out, int O) {
    __shared__ float Ws[8][64], Hs[8][128];
    const int b = blockIdx.x, n0 = blockIdx.y * 128, o0 = blockIdx.z * 64;
    const int t = threadIdx.x, tx = t & 15, ty = t >> 4;
    float acc[4][8] = {};
    const float* hb = h + (size_t)b * bstride;
    for (int c0 = 0; c0 < C; c0 += 8) {
#pragma unroll
        for (int q = 0; q < 2; ++q) {
            int e = t + q * 256;
            int oo = e >> 3, cc = e & 7;
            Ws[cc][oo] = ((c0 + cc) < C) ? A[(size_t)(o0 + oo) * astride + c0 + cc] : 0.f;
        }
        {
            int cc = t >> 5, nn4 = t & 31;
            float4 v = make_float4(0.f, 0.f, 0.f, 0.f);
            if (c0 + cc < C) v = *(const float4*)&hb[(size_t)(c0 + cc) * NV + n0 + nn4 * 4];
            *(float4*)&Hs[cc][nn4 * 4] = v;
        }
        __syncthreads();
#pragma unroll
        for (int c = 0; c < 8; ++c) {
            float4 wv = *(const float4*)&Ws[c][ty * 4];
            float ar[4] = {wv.x, wv.y, wv.z, wv.w};
            float br[8];
            float4 h0 = *(const float4*)&Hs[c][tx * 4];
            float4 h1 = *(const float4*)&Hs[c][64 + tx * 4];
            br[0] = h0.x; br[1] = h0.y; br[2] = h0.z; br[3] = h0.w;
            br[4] = h1.x; br[5] = h1.y; br[6] = h1.z; br[7] = h1.w;
#pragma unroll
            for (int a = 0; a < 4; ++a)
#pragma unroll
                for (int q = 0; q < 8; ++q) acc[a][q] += ar[a] * br[q];
        }
        __syncthreads();
    }
#pragma unroll
    for (int a = 0; a < 4; ++a) {
        int o = o0 + ty * 4 + a;
        float* outp = out + ((size_t)b * O + o) * NV + n0;
        float4 s0 = make_float4(acc[a][0], acc[a][1], acc[a][2], acc[a][3]);
        float4 s1 = make_float4(acc[a][4], acc[a][5], acc[a][6], acc[a][7]);
        *(float4*)&outp[tx * 4] = s0;
        *(float4*)&outp[64 + tx * 4] = s1;
    }
}

// ---------- h_out[b][o][n] = mean_k lrelu( a*(p[b][o][idx[n][k]] + d[b][o][n]) + c0 )
__global__ __launch_bounds__(256) void k_edge(const float* __restrict__ pd,
                                              const int* __restrict__ idx,
                                              const float* __restrict__ ga, const float* __restrict__ be,
                                              const float* __restrict__ mu, const float* __restrict__ va,
                                              float* __restrict__ out, int out_bstride, int O) {
    const int b = blockIdx.x;
    const int n = blockIdx.y * 256 + threadIdx.x;
    const int o0 = blockIdx.z * 4;
    const int* ip = idx + ((size_t)b * NV + n) * KNN;
    int jj[KNN];
#pragma unroll
    for (int k = 0; k < KNN; ++k) jj[k] = ip[k];
#pragma unroll
    for (int a = 0; a < 4; ++a) {
        const int o = o0 + a;
        const float al = ga[o] / sqrtf(va[o] + 1e-5f);
        const float c0 = be[o] - mu[o] * al;
        const float* pb = pd + ((size_t)b * 2 * O + o) * NV;
        const float dv  = pd[((size_t)b * 2 * O + O + o) * NV + n];
        float s = 0.f;
#pragma unroll
        for (int k = 0; k < KNN; ++k) {
            float y = fmaf(al, pb[jj[k]] + dv, c0);
            s += (y > 0.f) ? y : 0.2f * y;
        }
        out[(size_t)b * out_bstride + (size_t)o * NV + n] = s * (1.f / KNN);
    }
}

// ---------- pooled[b][o] = mean_n hf[b][o][n]
__global__ __launch_bounds__(256) void k_pool(const float* __restrict__ hf, float* __restrict__ pooled) {
    const int o = blockIdx.x, b = blockIdx.y;
    const float* hp = hf + ((size_t)b * 512 + o) * NV;
    float s = 0.f;
    for (int i = threadIdx.x; i < NV; i += 256) s += hp[i];
#pragma unroll
    for (int off = 32; off > 0; off >>= 1) s += __shfl_down(s, off, 64);
    __shared__ float red[4];
    if ((threadIdx.x & 63) == 0) red[threadIdx.x >> 6] = s;
    __syncthreads();
    if (threadIdx.x == 0)
        pooled[(size_t)b * 512 + o] = (red[0] + red[1] + red[2] + red[3]) * (1.f / NV);
}

// ---------- out[b][j] = sum_o pooled[b][o] * We[j][o]
__global__ __launch_bounds__(256) void k_final(const float* __restrict__ pooled, const float* __restrict__ We,
                                               float* __restrict__ out) {
    const int j = threadIdx.x, b = blockIdx.x;
    __shared__ float ps[512];
    for (int o = threadIdx.x; o < 512; o += 256) ps[o] = pooled[b * 512 + o];
    __syncthreads();
    float s = 0.f;
    for (int o = 0; o < 512; ++o) s += ps[o] * We[(size_t)j * 512 + o];
    out[b * 256 + j] = s;
}

extern "C" void kernel_launch(void* const* d_in, const int* in_sizes, int n_in,
                              void* d_out, int out_size, void* d_ws, size_t ws_size,
                              hipStream_t stream) {
    const float* x  = (const float*)d_in[0];
    const float* W0 = (const float*)d_in[1];
    const float* g0 = (const float*)d_in[2];
    const float* b0 = (const float*)d_in[3];
    const float* m0 = (const float*)d_in[4];
    const float* v0 = (const float*)d_in[5];
    const float* W1 = (const float*)d_in[6];
    const float* g1 = (const float*)d_in[7];
    const float* b1 = (const float*)d_in[8];
    const float* m1 = (const float*)d_in[9];
    const float* v1 = (const float*)d_in[10];
    const float* W2 = (const float*)d_in[11];
    const float* g2 = (const float*)d_in[12];
    const float* b2 = (const float*)d_in[13];
    const float* m2 = (const float*)d_in[14];
    const float* v2 = (const float*)d_in[15];
    const float* Wf = (const float*)d_in[16];
    const float* gf = (const float*)d_in[17];
    const float* bf = (const float*)d_in[18];
    const float* mf = (const float*)d_in[19];
    const float* vf = (const float*)d_in[20];
    const float* We = (const float*)d_in[21];

    float* ws = (float*)d_ws;
    float* hx     = ws;                          // 24576
    float* cat    = hx + 24576;                  // 3670016
    float* xx     = cat + 3670016;               // 8192
    int*   idx    = (int*)(xx + 8192);           // 163840 ints
    float* pd     = (float*)(idx + 163840);      // 8388608 (2O max = 1024)
    float* wb     = pd + 8388608;                // 458752
    float* hf     = wb + 458752;                 // 4194304
    float* pooled = hf + 4194304;                // 4096
    unsigned* sval = (unsigned*)(pooled + 4096); // 8192*4*20 = 655360
    int*      sidx = (int*)(sval + 655360);      // 655360

    k_transpose<<<96, 256, 0, stream>>>(x, hx);

    auto run_layer = [&](const float* h, int C, int bstride, const float* W,
                         const float* g, const float* be, const float* m, const float* v,
                         int O, float* outp, int obstride) {
        k_xx<<<32, 256, 0, stream>>>(h, xx, C, bstride);
        k_knn<<<512, 512, 0, stream>>>(h, xx, C, bstride, sval, sidx);
        k_merge<<<32, 256, 0, stream>>>(sval, sidx, idx);
        int pn = 2 * O * C;
        k_pack<<<(pn + 255) / 256, 256, 0, stream>>>(W, wb, C, O);
        k_gemm<<<dim3(8, 8, 2 * O / 64), 256, 0, stream>>>(wb, C, h, bstride, C, pd, 2 * O);
        k_edge<<<dim3(8, 4, O / 4), 256, 0, stream>>>(pd, idx, g, be, m, v, outp, obstride, O);
    };

    run_layer(hx, 3, 3 * NV, W0, g0, b0, m0, v0, 64, cat, 448 * NV);
    run_layer(cat, 64, 448 * NV, W1, g1, b1, m1, v1, 128, cat + 64 * NV, 448 * NV);
    run_layer(cat + 64 * NV, 128, 448 * NV, W2, g2, b2, m2, v2, 256, cat + 192 * NV, 448 * NV);
    run_layer(cat, 448, 448 * NV, Wf, gf, bf, mf, vf, 512, hf, 512 * NV);

    k_pool<<<dim3(512, 8), 256, 0, stream>>>(hf, pooled);
    k_final<<<8, 256, 0, stream>>>(pooled, We, (float*)d_out);
}

// Round 13
// 802.569 us; speedup vs baseline: 1.1656x; 1.0949x over previous
//
#include <hip/hip_runtime.h>
#include <cstdint>

#define KNN 20
#define BV 8
#define NV 1024

// ---- DPP wave64 reduces (rocPRIM pattern): result broadcast via readlane 63.
template <int CTRL>
__device__ __forceinline__ unsigned dppmax(unsigned x) {
    unsigned m = (unsigned)__builtin_amdgcn_update_dpp((int)x, (int)x, CTRL, 0xf, 0xf, false);
    return (x > m) ? x : m;
}
template <int CTRL>
__device__ __forceinline__ unsigned dppmin(unsigned x) {
    unsigned m = (unsigned)__builtin_amdgcn_update_dpp((int)x, (int)x, CTRL, 0xf, 0xf, false);
    return (x < m) ? x : m;
}
__device__ __forceinline__ unsigned wave_max_u32(unsigned x) {
    x = dppmax<0xB1>(x); x = dppmax<0x4E>(x); x = dppmax<0x141>(x);
    x = dppmax<0x140>(x); x = dppmax<0x142>(x); x = dppmax<0x143>(x);
    return (unsigned)__builtin_amdgcn_readlane((int)x, 63);
}
__device__ __forceinline__ unsigned wave_min_u32(unsigned x) {
    x = dppmin<0xB1>(x); x = dppmin<0x4E>(x); x = dppmin<0x141>(x);
    x = dppmin<0x140>(x); x = dppmin<0x142>(x); x = dppmin<0x143>(x);
    return (unsigned)__builtin_amdgcn_readlane((int)x, 63);
}

// ---------- transpose x [B,N,3] -> hx [B,3,N]
__global__ __launch_bounds__(256) void k_transpose(const float* __restrict__ x, float* __restrict__ hx) {
    int id = blockIdx.x * 256 + threadIdx.x;
    if (id >= BV * 3 * NV) return;
    int n = id % NV;
    int c = (id / NV) % 3;
    int b = id / (3 * NV);
    hx[id] = x[(b * NV + n) * 3 + c];
}

// ---------- xx[b][n] = sum_c h[b][c][n]^2
__global__ __launch_bounds__(256) void k_xx(const float* __restrict__ h, float* __restrict__ xx,
                                            int C, int bstride) {
    int id = blockIdx.x * 256 + threadIdx.x;
    int n = id % NV, b = id / NV;
    if (b >= BV) return;
    const float* hp = h + (size_t)b * bstride + n;
    float s = 0.f;
    for (int c = 0; c < C; ++c) { float v = hp[(size_t)c * NV]; s += v * v; }
    xx[b * NV + n] = s;
}

// ---------- FUSED kNN, FULL ROW: block = 16 rows x full 1024 cols, top-20 direct to idx.
// grid 512: b = bx&7 (XCD-local), tile = bx>>3. block 512 = 8 waves; wave w owns rows
// i0+2w..+1; lane owns 16 cands at j = g*256 + lane*4 + e (conflict-free b128 reads).
// A-rows are inside the staged panel (As == Bs slice) -> no separate A staging.
__global__ __launch_bounds__(512, 4) void k_knn(const float* __restrict__ h, const float* __restrict__ xx,
                                                int C, int bstride, int* __restrict__ idx) {
    __shared__ float Bs[8][1024];
    const int bx = blockIdx.x;
    const int b = bx & 7, tile = bx >> 3;
    const int i0 = tile * 16;
    const int t = threadIdx.x, lane = t & 63, w = t >> 6;
    const int irow = i0 + w * 2;
    float acc[2][16] = {};
    const float* hb = h + (size_t)b * bstride;

    for (int c0 = 0; c0 < C; c0 += 8) {
        __syncthreads();
#pragma unroll
        for (int r = 0; r < 4; ++r) {               // Bs[8][1024] = 2048 float4
            int e = r * 512 + t;
            int cc = e >> 8, jj = e & 255;
            float4 v = make_float4(0.f, 0.f, 0.f, 0.f);
            if (c0 + cc < C) v = *(const float4*)&hb[(size_t)(c0 + cc) * NV + jj * 4];
            *(float4*)&Bs[cc][jj * 4] = v;
        }
        __syncthreads();
#pragma unroll
        for (int c = 0; c < 8; ++c) {
            float2 arv = *(const float2*)&Bs[c][irow];     // wave-uniform broadcast
            float ar[2] = {arv.x, arv.y};
            float br[16];
#pragma unroll
            for (int g = 0; g < 4; ++g) {
                float4 bv = *(const float4*)&Bs[c][g * 256 + (lane << 2)];  // 16B/lane: conflict-free
                br[g * 4 + 0] = bv.x; br[g * 4 + 1] = bv.y;
                br[g * 4 + 2] = bv.z; br[g * 4 + 3] = bv.w;
            }
#pragma unroll
            for (int a = 0; a < 2; ++a)
#pragma unroll
                for (int q = 0; q < 16; ++q) acc[a][q] += ar[a] * br[q];
        }
    }

    // neg sqdist -> sortable uint, in place
    const float* xb = xx + b * NV;
    float xxj[16];
#pragma unroll
    for (int g = 0; g < 4; ++g) {
        float4 xv = *(const float4*)&xb[g * 256 + (lane << 2)];
        xxj[g * 4 + 0] = xv.x; xxj[g * 4 + 1] = xv.y;
        xxj[g * 4 + 2] = xv.z; xxj[g * 4 + 3] = xv.w;
    }
    unsigned ua[2][16];
#pragma unroll
    for (int a = 0; a < 2; ++a) {
        float xi = xb[irow + a];
#pragma unroll
        for (int q = 0; q < 16; ++q) {
            float d = 2.f * acc[a][q] - xi - xxj[q];
            unsigned u = __float_as_uint(d);
            ua[a][q] = ((int)u < 0) ? ~u : (u | 0x80000000u);   // sortable: bigger = nearer
        }
    }

    // ---- wave-parallel top-20 per row, 2 rows interleaved, all-VALU.
    int* opb = idx + ((size_t)(b * NV + irow)) * KNN;
#pragma unroll 1
    for (int s = 0; s < KNN; ++s) {
#pragma unroll
        for (int a = 0; a < 2; ++a) {
            // 16-wide tournament tree; strict > keeps lower q (= lower j within lane) on ties
            unsigned w0[8]; int p0[8];
#pragma unroll
            for (int i = 0; i < 8; ++i) {
                bool g = ua[a][2 * i + 1] > ua[a][2 * i];
                w0[i] = g ? ua[a][2 * i + 1] : ua[a][2 * i];
                p0[i] = g ? 2 * i + 1 : 2 * i;
            }
            unsigned w1[4]; int p1[4];
#pragma unroll
            for (int i = 0; i < 4; ++i) {
                bool g = w1[0], gg = w0[2 * i + 1] > w0[2 * i];
                (void)g;
                w1[i] = gg ? w0[2 * i + 1] : w0[2 * i];
                p1[i] = gg ? p0[2 * i + 1] : p0[2 * i];
            }
            unsigned w2[2]; int p2[2];
#pragma unroll
            for (int i = 0; i < 2; ++i) {
                bool gg = w1[2 * i + 1] > w1[2 * i];
                w2[i] = gg ? w1[2 * i + 1] : w1[2 * i];
                p2[i] = gg ? p1[2 * i + 1] : p1[2 * i];
            }
            bool gf = w2[1] > w2[0];
            unsigned su = gf ? w2[1] : w2[0];
            int bq = gf ? p2[1] : p2[0];

            unsigned gmax = wave_max_u32(su);
            int myj = ((bq >> 2) << 8) + (lane << 2) + (bq & 3);
            unsigned cand = (su == gmax) ? (unsigned)myj : 0xFFFFFFFFu;
            int j = (int)wave_min_u32(cand);            // exact lowest-j among value ties
            if (lane == 0) opb[a * KNN + s] = j;
            int wq = (cand == (unsigned)j) ? bq : 99;   // unique winner lane poisons its slot
#pragma unroll
            for (int q = 0; q < 16; ++q)
                if (wq == q) ua[a][q] = 0u;             // 0 = smaller than any real cand
        }
    }
}

// ---------- pack A = [ Wl ; Wr - Wl ]  (2O x C)
__global__ __launch_bounds__(256) void k_pack(const float* __restrict__ W, float* __restrict__ wb,
                                              int C, int O) {
    int id = blockIdx.x * 256 + threadIdx.x;
    if (id >= 2 * O * C) return;
    int c = id % C, o = (id / C) % O, half = id / (C * O);
    float wl = W[(size_t)o * 2 * C + c];
    wb[id] = half ? (W[(size_t)o * 2 * C + C + c] - wl) : wl;
}

// ---------- out[b][o][n] = sum_c A[o][c] * h[b][c][n]   (64x128 tile, 4x8 micro)
__global__ __launch_bounds__(256) void k_gemm(const float* __restrict__ A, int astride,
                                              const float* __restrict__ h, int bstride, int C,
                                              float* __restrict__ out, int O) {
    __shared__ float Ws[8][64], Hs[8][128];
    const int b = blockIdx.x, n0 = blockIdx.y * 128, o0 = blockIdx.z * 64;
    const int t = threadIdx.x, tx = t & 15, ty = t >> 4;
    float acc[4][8] = {};
    const float* hb = h + (size_t)b * bstride;
    for (int c0 = 0; c0 < C; c0 += 8) {
#pragma unroll
        for (int q = 0; q < 2; ++q) {
            int e = t + q * 256;
            int oo = e >> 3, cc = e & 7;
            Ws[cc][oo] = ((c0 + cc) < C) ? A[(size_t)(o0 + oo) * astride + c0 + cc] : 0.f;
        }
        {
            int cc = t >> 5, nn4 = t & 31;
            float4 v = make_float4(0.f, 0.f, 0.f, 0.f);
            if (c0 + cc < C) v = *(const float4*)&hb[(size_t)(c0 + cc) * NV + n0 + nn4 * 4];
            *(float4*)&Hs[cc][nn4 * 4] = v;
        }
        __syncthreads();
#pragma unroll
        for (int c = 0; c < 8; ++c) {
            float4 wv = *(const float4*)&Ws[c][ty * 4];
            float ar[4] = {wv.x, wv.y, wv.z, wv.w};
            float br[8];
            float4 h0 = *(const float4*)&Hs[c][tx * 4];
            float4 h1 = *(const float4*)&Hs[c][64 + tx * 4];
            br[0] = h0.x; br[1] = h0.y; br[2] = h0.z; br[3] = h0.w;
            br[4] = h1.x; br[5] = h1.y; br[6] = h1.z; br[7] = h1.w;
#pragma unroll
            for (int a = 0; a < 4; ++a)
#pragma unroll
                for (int q = 0; q < 8; ++q) acc[a][q] += ar[a] * br[q];
        }
        __syncthreads();
    }
#pragma unroll
    for (int a = 0; a < 4; ++a) {
        int o = o0 + ty * 4 + a;
        float* outp = out + ((size_t)b * O + o) * NV + n0;
        float4 s0 = make_float4(acc[a][0], acc[a][1], acc[a][2], acc[a][3]);
        float4 s1 = make_float4(acc[a][4], acc[a][5], acc[a][6], acc[a][7]);
        *(float4*)&outp[tx * 4] = s0;
        *(float4*)&outp[64 + tx * 4] = s1;
    }
}

// ---------- h_out[b][o][n] = mean_k lrelu( a*(p[b][o][idx[n][k]] + d[b][o][n]) + c0 )
__global__ __launch_bounds__(256) void k_edge(const float* __restrict__ pd,
                                              const int* __restrict__ idx,
                                              const float* __restrict__ ga, const float* __restrict__ be,
                                              const float* __restrict__ mu, const float* __restrict__ va,
                                              float* __restrict__ out, int out_bstride, int O) {
    const int b = blockIdx.x;
    const int n = blockIdx.y * 256 + threadIdx.x;
    const int o0 = blockIdx.z * 4;
    const int* ip = idx + ((size_t)b * NV + n) * KNN;
    int jj[KNN];
#pragma unroll
    for (int k = 0; k < KNN; ++k) jj[k] = ip[k];
#pragma unroll
    for (int a = 0; a < 4; ++a) {
        const int o = o0 + a;
        const float al = ga[o] / sqrtf(va[o] + 1e-5f);
        const float c0 = be[o] - mu[o] * al;
        const float* pb = pd + ((size_t)b * 2 * O + o) * NV;
        const float dv  = pd[((size_t)b * 2 * O + O + o) * NV + n];
        float s = 0.f;
#pragma unroll
        for (int k = 0; k < KNN; ++k) {
            float y = fmaf(al, pb[jj[k]] + dv, c0);
            s += (y > 0.f) ? y : 0.2f * y;
        }
        out[(size_t)b * out_bstride + (size_t)o * NV + n] = s * (1.f / KNN);
    }
}

// ---------- pooled[b][o] = mean_n hf[b][o][n]
__global__ __launch_bounds__(256) void k_pool(const float* __restrict__ hf, float* __restrict__ pooled) {
    const int o = blockIdx.x, b = blockIdx.y;
    const float* hp = hf + ((size_t)b * 512 + o) * NV;
    float s = 0.f;
    for (int i = threadIdx.x; i < NV; i += 256) s += hp[i];
#pragma unroll
    for (int off = 32; off > 0; off >>= 1) s += __shfl_down(s, off, 64);
    __shared__ float red[4];
    if ((threadIdx.x & 63) == 0) red[threadIdx.x >> 6] = s;
    __syncthreads();
    if (threadIdx.x == 0)
        pooled[(size_t)b * 512 + o] = (red[0] + red[1] + red[2] + red[3]) * (1.f / NV);
}

// ---------- out[b][j] = sum_o pooled[b][o] * We[j][o]
__global__ __launch_bounds__(256) void k_final(const float* __restrict__ pooled, const float* __restrict__ We,
                                               float* __restrict__ out) {
    const int j = threadIdx.x, b = blockIdx.x;
    __shared__ float ps[512];
    for (int o = threadIdx.x; o < 512; o += 256) ps[o] = pooled[b * 512 + o];
    __syncthreads();
    float s = 0.f;
    for (int o = 0; o < 512; ++o) s += ps[o] * We[(size_t)j * 512 + o];
    out[b * 256 + j] = s;
}

extern "C" void kernel_launch(void* const* d_in, const int* in_sizes, int n_in,
                              void* d_out, int out_size, void* d_ws, size_t ws_size,
                              hipStream_t stream) {
    const float* x  = (const float*)d_in[0];
    const float* W0 = (const float*)d_in[1];
    const float* g0 = (const float*)d_in[2];
    const float* b0 = (const float*)d_in[3];
    const float* m0 = (const float*)d_in[4];
    const float* v0 = (const float*)d_in[5];
    const float* W1 = (const float*)d_in[6];
    const float* g1 = (const float*)d_in[7];
    const float* b1 = (const float*)d_in[8];
    const float* m1 = (const float*)d_in[9];
    const float* v1 = (const float*)d_in[10];
    const float* W2 = (const float*)d_in[11];
    const float* g2 = (const float*)d_in[12];
    const float* b2 = (const float*)d_in[13];
    const float* m2 = (const float*)d_in[14];
    const float* v2 = (const float*)d_in[15];
    const float* Wf = (const float*)d_in[16];
    const float* gf = (const float*)d_in[17];
    const float* bf = (const float*)d_in[18];
    const float* mf = (const float*)d_in[19];
    const float* vf = (const float*)d_in[20];
    const float* We = (const float*)d_in[21];

    float* ws = (float*)d_ws;
    float* hx     = ws;                          // 24576
    float* cat    = hx + 24576;                  // 3670016
    float* xx     = cat + 3670016;               // 8192
    int*   idx    = (int*)(xx + 8192);           // 163840 ints
    float* pd     = (float*)(idx + 163840);      // 8388608 (2O max = 1024)
    float* wb     = pd + 8388608;                // 458752
    float* hf     = wb + 458752;                 // 4194304
    float* pooled = hf + 4194304;                // 4096

    k_transpose<<<96, 256, 0, stream>>>(x, hx);

    auto run_layer = [&](const float* h, int C, int bstride, const float* W,
                         const float* g, const float* be, const float* m, const float* v,
                         int O, float* outp, int obstride) {
        k_xx<<<32, 256, 0, stream>>>(h, xx, C, bstride);
        k_knn<<<512, 512, 0, stream>>>(h, xx, C, bstride, idx);
        int pn = 2 * O * C;
        k_pack<<<(pn + 255) / 256, 256, 0, stream>>>(W, wb, C, O);
        k_gemm<<<dim3(8, 8, 2 * O / 64), 256, 0, stream>>>(wb, C, h, bstride, C, pd, 2 * O);
        k_edge<<<dim3(8, 4, O / 4), 256, 0, stream>>>(pd, idx, g, be, m, v, outp, obstride, O);
    };

    run_layer(hx, 3, 3 * NV, W0, g0, b0, m0, v0, 64, cat, 448 * NV);
    run_layer(cat, 64, 448 * NV, W1, g1, b1, m1, v1, 128, cat + 64 * NV, 448 * NV);
    run_layer(cat + 64 * NV, 128, 448 * NV, W2, g2, b2, m2, v2, 256, cat + 192 * NV, 448 * NV);
    run_layer(cat, 448, 448 * NV, Wf, gf, bf, mf, vf, 512, hf, 512 * NV);

    k_pool<<<dim3(512, 8), 256, 0, stream>>>(hf, pooled);
    k_final<<<8, 256, 0, stream>>>(pooled, We, (float*)d_out);
}